// Round 14
// baseline (771.893 us; speedup 1.0000x reference)
//
#include <hip/hip_runtime.h>
#include <math.h>

#define S_LEN 2048
#define HIDDEN 4096
#define NHEAD 32
#define D_NOPE 128
#define D_ROPE 64
#define D_V 128
#define D_QK 192
#define QRANK 1536
#define KVRANK 512
#define IDXH 16
#define IDXD 128
#define KSEL 1024
#define NIDX 2304  // 2048 (wq) + 128 (wk) + 16 (weights) + 112 pad

typedef __attribute__((ext_vector_type(8))) short bf16x8;
typedef __attribute__((ext_vector_type(4))) float f32x4;
typedef __attribute__((ext_vector_type(4))) unsigned short u16x4;

__device__ __forceinline__ unsigned short f2b(float f) {
    union { float f; unsigned int u; } x; x.f = f;
    unsigned int r = x.u + 0x7FFFu + ((x.u >> 16) & 1u);
    return (unsigned short)(r >> 16);
}
__device__ __forceinline__ float b2f(unsigned short u) {
    union { unsigned int u; float f; } x; x.u = ((unsigned int)u) << 16; return x.f;
}

// global -> LDS direct load, 16B per lane. LDS dest = wave-uniform base + lane*16.
__device__ __forceinline__ void gload16(const void* g, const void* l) {
    __builtin_amdgcn_global_load_lds(
        (const __attribute__((address_space(1))) unsigned int*)(unsigned long long)g,
        (__attribute__((address_space(3))) unsigned int*)(unsigned int)(unsigned long long)l,
        16, 0, 0);
}

// ---------------------------------------------------------------------------
// bf16 MFMA GEMM: C[M,N] = alpha * A[M,K] @ Bt[N,K]^T. 128x128 tile.
// Double-buffered counted-vmcnt pipeline + bijective XCD-chunk swizzle (T1).
// Requires grid size % 8 == 0.
// ---------------------------------------------------------------------------
template <int OUT_BF16>
__global__ __launch_bounds__(256) void gemm_bf16(const unsigned short* __restrict__ A,
                                                 const unsigned short* __restrict__ Bt,
                                                 void* __restrict__ Cv,
                                                 int K, int ldc, float alpha) {
    __shared__ __align__(16) unsigned char lds[32768];  // 2 x (As 8KB | Bs 8KB)
    const int tid = threadIdx.x;
    const int w = tid >> 6, lane = tid & 63;
    const int lr = lane & 15, g = lane >> 4;
    const int gx = gridDim.x;
    const int nwg = gx * gridDim.y;
    const int flat = blockIdx.y * gx + blockIdx.x;
    const int swz = (flat & 7) * (nwg >> 3) + (flat >> 3);
    const int bm = (swz / gx) * 128, bn = (swz % gx) * 128;
    const int wm = (w >> 1) * 64, wn = (w & 1) * 64;

    f32x4 acc[4][4];
#pragma unroll
    for (int i = 0; i < 4; ++i)
#pragma unroll
        for (int j = 0; j < 4; ++j) acc[i][j] = (f32x4){0.f, 0.f, 0.f, 0.f};

    int a_off[2], b_off[2];
#pragma unroll
    for (int issue = 0; issue < 2; ++issue) {
        const int off = issue * 4096 + w * 1024 + lane * 16;
        const int row = off >> 6, slot = (off >> 4) & 3;
        a_off[issue] = (bm + row) * K + ((slot ^ (row & 3)) << 3);
        b_off[issue] = (bn + row) * K + ((slot ^ (row & 3)) << 3);
    }

    const int KT = K >> 5;
    auto stage = [&](int t, int buf) {
        const int k0 = t << 5;
        unsigned char* l = lds + buf * 16384;
        gload16(A + a_off[0] + k0, l + w * 1024);
        gload16(A + a_off[1] + k0, l + 4096 + w * 1024);
        gload16(Bt + b_off[0] + k0, l + 8192 + w * 1024);
        gload16(Bt + b_off[1] + k0, l + 8192 + 4096 + w * 1024);
    };

    stage(0, 0);
    for (int t = 0; t < KT; ++t) {
        if (t + 1 < KT) {
            stage(t + 1, (t + 1) & 1);
            asm volatile("s_waitcnt vmcnt(4)" ::: "memory");  // tile t landed
        } else {
            asm volatile("s_waitcnt vmcnt(0)" ::: "memory");
        }
        __syncthreads();
        const unsigned char* l = lds + (t & 1) * 16384;

        bf16x8 af[4], bfr[4];
#pragma unroll
        for (int i = 0; i < 4; ++i) {
            const int rowA = wm + i * 16 + lr;
            af[i] = *(const bf16x8*)(l + rowA * 64 + ((g ^ (rowA & 3)) << 4));
            const int rowB = wn + i * 16 + lr;
            bfr[i] = *(const bf16x8*)(l + 8192 + rowB * 64 + ((g ^ (rowB & 3)) << 4));
        }
#pragma unroll
        for (int i = 0; i < 4; ++i)
#pragma unroll
            for (int j = 0; j < 4; ++j)
                acc[i][j] = __builtin_amdgcn_mfma_f32_16x16x32_bf16(af[i], bfr[j], acc[i][j], 0, 0, 0);
        __syncthreads();
    }

#pragma unroll
    for (int i = 0; i < 4; ++i) {
        const int m = bm + wm + i * 16 + g * 4;
#pragma unroll
        for (int j = 0; j < 4; ++j) {
            const int n = bn + wn + j * 16 + lr;
            if (OUT_BF16) {
                unsigned short* Cb = (unsigned short*)Cv;
#pragma unroll
                for (int r = 0; r < 4; ++r)
                    Cb[(size_t)(m + r) * ldc + n] = f2b(acc[i][j][r] * alpha);
            } else {
                float* Cf = (float*)Cv;
#pragma unroll
                for (int r = 0; r < 4; ++r)
                    Cf[(size_t)(m + r) * ldc + n] = acc[i][j][r] * alpha;
            }
        }
    }
}

// ---------------------------------------------------------------------------
// kv_b GEMM with fused pack epilogue. A = kvn16 [2048][512], Bt = kvbT
// [8192][512]. Even 128-col blocks (d<128 of a head) -> kb16[h][s][192] nope;
// odd blocks (v) -> LDS-transpose -> vT[h*128+d][s]. Grid (64,16).
// ---------------------------------------------------------------------------
__global__ __launch_bounds__(256) void gemm_kvb(const unsigned short* __restrict__ A,
                                                const unsigned short* __restrict__ Bt,
                                                unsigned short* __restrict__ kb16,
                                                unsigned short* __restrict__ vT) {
    __shared__ __align__(16) unsigned char lds[34816];  // loop: 32KB dbuf; epi: 128x136 u16
    const int tid = threadIdx.x;
    const int w = tid >> 6, lane = tid & 63;
    const int lr = lane & 15, g = lane >> 4;
    const int gx = gridDim.x;
    const int nwg = gx * gridDim.y;
    const int flat = blockIdx.y * gx + blockIdx.x;
    const int swz = (flat & 7) * (nwg >> 3) + (flat >> 3);
    const int bm = (swz / gx) * 128, bn = (swz % gx) * 128;
    const int wm = (w >> 1) * 64, wn = (w & 1) * 64;
    const int K = KVRANK;

    f32x4 acc[4][4];
#pragma unroll
    for (int i = 0; i < 4; ++i)
#pragma unroll
        for (int j = 0; j < 4; ++j) acc[i][j] = (f32x4){0.f, 0.f, 0.f, 0.f};

    int a_off[2], b_off[2];
#pragma unroll
    for (int issue = 0; issue < 2; ++issue) {
        const int off = issue * 4096 + w * 1024 + lane * 16;
        const int row = off >> 6, slot = (off >> 4) & 3;
        a_off[issue] = (bm + row) * K + ((slot ^ (row & 3)) << 3);
        b_off[issue] = (bn + row) * K + ((slot ^ (row & 3)) << 3);
    }

    const int KT = K >> 5;
    auto stage = [&](int t, int buf) {
        const int k0 = t << 5;
        unsigned char* l = lds + buf * 16384;
        gload16(A + a_off[0] + k0, l + w * 1024);
        gload16(A + a_off[1] + k0, l + 4096 + w * 1024);
        gload16(Bt + b_off[0] + k0, l + 8192 + w * 1024);
        gload16(Bt + b_off[1] + k0, l + 8192 + 4096 + w * 1024);
    };

    stage(0, 0);
    for (int t = 0; t < KT; ++t) {
        if (t + 1 < KT) {
            stage(t + 1, (t + 1) & 1);
            asm volatile("s_waitcnt vmcnt(4)" ::: "memory");
        } else {
            asm volatile("s_waitcnt vmcnt(0)" ::: "memory");
        }
        __syncthreads();
        const unsigned char* l = lds + (t & 1) * 16384;

        bf16x8 af[4], bfr[4];
#pragma unroll
        for (int i = 0; i < 4; ++i) {
            const int rowA = wm + i * 16 + lr;
            af[i] = *(const bf16x8*)(l + rowA * 64 + ((g ^ (rowA & 3)) << 4));
            const int rowB = wn + i * 16 + lr;
            bfr[i] = *(const bf16x8*)(l + 8192 + rowB * 64 + ((g ^ (rowB & 3)) << 4));
        }
#pragma unroll
        for (int i = 0; i < 4; ++i)
#pragma unroll
            for (int j = 0; j < 4; ++j)
                acc[i][j] = __builtin_amdgcn_mfma_f32_16x16x32_bf16(af[i], bfr[j], acc[i][j], 0, 0, 0);
        __syncthreads();
    }

    const int h = bn >> 8;
    if ((bn & 128) == 0) {
        // k_nope columns -> kb16[h][s][192], d = wn + j*16 + lr (0..127)
#pragma unroll
        for (int i = 0; i < 4; ++i) {
            const int m = bm + wm + i * 16 + g * 4;
#pragma unroll
            for (int j = 0; j < 4; ++j) {
                const int dl = wn + j * 16 + lr;
#pragma unroll
                for (int r = 0; r < 4; ++r)
                    kb16[((size_t)h * S_LEN + m + r) * D_QK + dl] = f2b(acc[i][j][r]);
            }
        }
    } else {
        // V columns -> transpose via LDS -> vT[h*128+d][s]
        unsigned short(*T)[136] = (unsigned short(*)[136])lds;
#pragma unroll
        for (int i = 0; i < 4; ++i) {
            const int ml = wm + i * 16 + g * 4;
#pragma unroll
            for (int j = 0; j < 4; ++j) {
                const int dl = wn + j * 16 + lr;
#pragma unroll
                for (int r = 0; r < 4; ++r) T[dl][ml + r] = f2b(acc[i][j][r]);
            }
        }
        __syncthreads();
        const int row = tid >> 1, half = tid & 1;
        unsigned short* dst = vT + (size_t)(h * 128 + row) * S_LEN + bm + half * 64;
        const unsigned short* src = &T[row][half * 64];
#pragma unroll
        for (int u = 0; u < 8; ++u)  // full 64 u16 per half-row
            *(uint4*)(dst + u * 8) = *(const uint4*)(src + u * 8);
    }
}

// ---------------------------------------------------------------------------
// Split-precision (hi/lo bf16) MFMA GEMM for the indexer (unchanged r9).
// ---------------------------------------------------------------------------
__global__ __launch_bounds__(256) void gemm_split(const unsigned short* __restrict__ Ah,
                                                  const unsigned short* __restrict__ Al,
                                                  const unsigned short* __restrict__ Bh,
                                                  const unsigned short* __restrict__ Bl,
                                                  float* __restrict__ C0,
                                                  float* __restrict__ C1) {
    const int K = HIDDEN, ldc = NIDX;
    const int bid = blockIdx.x;              // 304 = 8 * 38
    const int wf = (bid & 7) * 38 + (bid >> 3);
    const int kz = (wf >= 152) ? 1 : 0;
    const int wgid = wf - kz * 152;
    int x, y;
    if (wgid < 144) { y = 8 + wgid / 18; x = wgid % 18; }
    else            { x = 16; y = wgid - 144; }
    const int bm = y * 128, bn = x * 128;
    float* __restrict__ C = kz ? C1 : C0;

    __shared__ __align__(16) unsigned char lds[65536];
    const int tid = threadIdx.x;
    const int w = tid >> 6, lane = tid & 63;
    const int lr = lane & 15, g = lane >> 4;
    const int wm = (w >> 1) * 64, wn = (w & 1) * 64;

    f32x4 acc[4][4];
#pragma unroll
    for (int i = 0; i < 4; ++i)
#pragma unroll
        for (int j = 0; j < 4; ++j) acc[i][j] = (f32x4){0.f, 0.f, 0.f, 0.f};

    int a_off[2], b_off[2];
#pragma unroll
    for (int issue = 0; issue < 2; ++issue) {
        const int off = issue * 4096 + w * 1024 + lane * 16;
        const int row = off >> 6, slot = (off >> 4) & 3;
        a_off[issue] = (bm + row) * K + ((slot ^ (row & 3)) << 3) + kz * 2048;
        b_off[issue] = (bn + row) * K + ((slot ^ (row & 3)) << 3) + kz * 2048;
    }

    const int KT = 2048 >> 5;
    auto stage = [&](int t, int buf) {
        const int k0 = t << 5;
        unsigned char* l = lds + buf * 32768;
        gload16(Ah + a_off[0] + k0, l + w * 1024);
        gload16(Ah + a_off[1] + k0, l + 4096 + w * 1024);
        gload16(Al + a_off[0] + k0, l + 8192 + w * 1024);
        gload16(Al + a_off[1] + k0, l + 8192 + 4096 + w * 1024);
        gload16(Bh + b_off[0] + k0, l + 16384 + w * 1024);
        gload16(Bh + b_off[1] + k0, l + 16384 + 4096 + w * 1024);
        gload16(Bl + b_off[0] + k0, l + 24576 + w * 1024);
        gload16(Bl + b_off[1] + k0, l + 24576 + 4096 + w * 1024);
    };

    stage(0, 0);
    for (int t = 0; t < KT; ++t) {
        if (t + 1 < KT) {
            stage(t + 1, (t + 1) & 1);
            asm volatile("s_waitcnt vmcnt(8)" ::: "memory");
        } else {
            asm volatile("s_waitcnt vmcnt(0)" ::: "memory");
        }
        __syncthreads();
        const unsigned char* l = lds + (t & 1) * 32768;

        bf16x8 afh[4], afl[4], bfh[4], bfl[4];
#pragma unroll
        for (int i = 0; i < 4; ++i) {
            const int rowA = wm + i * 16 + lr;
            const int offA = rowA * 64 + ((g ^ (rowA & 3)) << 4);
            afh[i] = *(const bf16x8*)(l + offA);
            afl[i] = *(const bf16x8*)(l + 8192 + offA);
            const int rowB = wn + i * 16 + lr;
            const int offB = rowB * 64 + ((g ^ (rowB & 3)) << 4);
            bfh[i] = *(const bf16x8*)(l + 16384 + offB);
            bfl[i] = *(const bf16x8*)(l + 24576 + offB);
        }
#pragma unroll
        for (int i = 0; i < 4; ++i)
#pragma unroll
            for (int j = 0; j < 4; ++j) {
                acc[i][j] = __builtin_amdgcn_mfma_f32_16x16x32_bf16(afh[i], bfh[j], acc[i][j], 0, 0, 0);
                acc[i][j] = __builtin_amdgcn_mfma_f32_16x16x32_bf16(afh[i], bfl[j], acc[i][j], 0, 0, 0);
                acc[i][j] = __builtin_amdgcn_mfma_f32_16x16x32_bf16(afl[i], bfh[j], acc[i][j], 0, 0, 0);
            }
        __syncthreads();
    }

#pragma unroll
    for (int i = 0; i < 4; ++i) {
        const int m = bm + wm + i * 16 + g * 4;
#pragma unroll
        for (int j = 0; j < 4; ++j) {
            const int n = bn + wn + j * 16 + lr;
#pragma unroll
            for (int r = 0; r < 4; ++r)
                C[(size_t)(m + r) * ldc + n] = acc[i][j][r];
        }
    }
}

// ---------------------------------------------------------------------------
// fp32 -> (hi, lo) bf16 pair, 4 elems/thread
// ---------------------------------------------------------------------------
__global__ __launch_bounds__(256) void conv_split_h(const float* __restrict__ src,
                                                    unsigned short* __restrict__ dhi,
                                                    unsigned short* __restrict__ dlo) {
    const int i = blockIdx.x * 256 + threadIdx.x;
    const float4 v = ((const float4*)src)[i];
    u16x4 hi, lo;
    const float xs[4] = {v.x, v.y, v.z, v.w};
#pragma unroll
    for (int j = 0; j < 4; ++j) {
        const unsigned short h = f2b(xs[j]);
        hi[j] = h;
        lo[j] = f2b(xs[j] - b2f(h));
    }
    *(u16x4*)(dhi + (size_t)i * 4) = hi;
    *(u16x4*)(dlo + (size_t)i * 4) = lo;
}

// Sum split-K partials, then split (unchanged r9).
__global__ __launch_bounds__(256) void conv_split_iq(const float* __restrict__ C0,
                                                     const float* __restrict__ C1,
                                                     unsigned short* __restrict__ iqh,
                                                     unsigned short* __restrict__ iql,
                                                     unsigned short* __restrict__ ikh,
                                                     unsigned short* __restrict__ ikl,
                                                     float* __restrict__ iwbuf) {
    const int i = blockIdx.x * 256 + threadIdx.x;  // over 2048*548
    const int row = i / 548, c4 = (i - row * 548) * 4;
    const float4 v0 = *(const float4*)(C0 + (size_t)row * NIDX + c4);
    const float4 v1 = *(const float4*)(C1 + (size_t)row * NIDX + c4);
    const float xs[4] = {v0.x + v1.x, v0.y + v1.y, v0.z + v1.z, v0.w + v1.w};
    if (c4 >= 2176) {
        *(float4*)(iwbuf + (size_t)row * 16 + (c4 - 2176)) =
            (float4){xs[0], xs[1], xs[2], xs[3]};
        return;
    }
    u16x4 hi, lo;
#pragma unroll
    for (int j = 0; j < 4; ++j) {
        const unsigned short h = f2b(xs[j]);
        hi[j] = h;
        lo[j] = f2b(xs[j] - b2f(h));
    }
    if (c4 < 2048) {
        *(u16x4*)(iqh + (size_t)row * 2048 + c4) = hi;
        *(u16x4*)(iql + (size_t)row * 2048 + c4) = lo;
    } else {
        *(u16x4*)(ikh + (size_t)row * 128 + c4 - 2048) = hi;
        *(u16x4*)(ikl + (size_t)row * 128 + c4 - 2048) = lo;
    }
}

// ---------------------------------------------------------------------------
// Weight transpose-convert kernels (unchanged)
// ---------------------------------------------------------------------------
__global__ __launch_bounds__(256) void wtrans(const float* __restrict__ W,
                                              unsigned short* __restrict__ Bt,
                                              int K, int Nsrc) {
    const int n0 = blockIdx.x * 64, k0 = blockIdx.y * 64;
    __shared__ unsigned short lv[64][72];
    const int tid = threadIdx.x;
#pragma unroll
    for (int it = 0; it < 16; ++it) {
        const int idx = tid + it * 256;
        const int kr = idx >> 6, n = idx & 63;
        const float v = (n0 + n < Nsrc) ? W[(size_t)(k0 + kr) * Nsrc + n0 + n] : 0.f;
        lv[n][kr] = f2b(v);
    }
    __syncthreads();
#pragma unroll
    for (int it = 0; it < 16; ++it) {
        const int idx = tid + it * 256;
        const int n = idx >> 6, kk = idx & 63;
        Bt[(size_t)(n0 + n) * K + k0 + kk] = lv[n][kk];
    }
}

__global__ __launch_bounds__(256) void wtrans_split(const float* __restrict__ W,
                                                    unsigned short* __restrict__ Bth,
                                                    unsigned short* __restrict__ Btl,
                                                    int K, int Nsrc) {
    const int n0 = blockIdx.x * 64, k0 = blockIdx.y * 64;
    __shared__ float lv[64][65];
    const int tid = threadIdx.x;
#pragma unroll
    for (int it = 0; it < 16; ++it) {
        const int idx = tid + it * 256;
        const int kr = idx >> 6, n = idx & 63;
        lv[n][kr] = (n0 + n < Nsrc) ? W[(size_t)(k0 + kr) * Nsrc + n0 + n] : 0.f;
    }
    __syncthreads();
#pragma unroll
    for (int it = 0; it < 16; ++it) {
        const int idx = tid + it * 256;
        const int n = idx >> 6, kk = idx & 63;
        const float x = lv[n][kk];
        const unsigned short h = f2b(x);
        Bth[(size_t)(n0 + n) * K + k0 + kk] = h;
        Btl[(size_t)(n0 + n) * K + k0 + kk] = f2b(x - b2f(h));
    }
}

// ---------------------------------------------------------------------------
// RMSNorm fp32 in (strided) -> bf16 out
// ---------------------------------------------------------------------------
__global__ __launch_bounds__(256) void rmsnormb(const float* __restrict__ in,
                                                const float* __restrict__ w,
                                                unsigned short* __restrict__ out,
                                                int W, int in_stride) {
    const int row = blockIdx.x;
    const int tid = threadIdx.x;
    const float* x = in + (size_t)row * in_stride;
    float ss = 0.f;
    for (int i = tid; i < W; i += 256) {
        float v = x[i];
        ss += v * v;
    }
    __shared__ float red[256];
    red[tid] = ss;
    __syncthreads();
    for (int s = 128; s > 0; s >>= 1) {
        if (tid < s) red[tid] += red[tid + s];
        __syncthreads();
    }
    const float scale = rsqrtf(red[0] / (float)W + 1e-5f);
    for (int i = tid; i < W; i += 256) out[(size_t)row * W + i] = f2b(x[i] * scale * w[i]);
}

// ---------------------------------------------------------------------------
// RoPE kernels
// ---------------------------------------------------------------------------
__global__ __launch_bounds__(256) void rope_q16(unsigned short* __restrict__ q) {
    const int idx = blockIdx.x * 256 + threadIdx.x;
    if (idx >= S_LEN * NHEAD * (D_ROPE / 2)) return;
    const int i = idx & 31;
    const int h = (idx >> 5) & 31;
    const int s = idx >> 10;
    const float inv = __expf(-(float)i * (logf(10000.f) / 32.f));
    const float ang = (float)s * inv;
    const float cs = cosf(ang), sn = sinf(ang);
    unsigned short* p = q + (size_t)s * (NHEAD * D_QK) + h * D_QK + D_NOPE + 2 * i;
    const float x0 = b2f(p[0]), x1 = b2f(p[1]);
    p[0] = f2b(x0 * cs - x1 * sn);
    p[1] = f2b(x1 * cs + x0 * sn);
}

// RoPE k_pe from C1 (stride 2176, cols 2048..2111) broadcast into all heads of
// kb16[h][s][128+2i..].
__global__ __launch_bounds__(256) void rope_k16b(const float* __restrict__ C1,
                                                 unsigned short* __restrict__ kb16) {
    const int idx = blockIdx.x * 256 + threadIdx.x;
    const int i = idx & 31;
    const int s = (idx >> 5) & 2047;
    const int h = idx >> 16;
    const float inv = __expf(-(float)i * (logf(10000.f) / 32.f));
    const float ang = (float)s * inv;
    const float cs = cosf(ang), sn = sinf(ang);
    const float* p = C1 + (size_t)s * 2176 + 2048 + 2 * i;
    const float x0 = p[0], x1 = p[1];
    unsigned short* o = kb16 + ((size_t)h * S_LEN + s) * D_QK + D_NOPE + 2 * i;
    o[0] = f2b(x0 * cs - x1 * sn);
    o[1] = f2b(x1 * cs + x0 * sn);
}

// ---------------------------------------------------------------------------
// Indexer scores via split-bf16 MFMA (unchanged r9).
// ---------------------------------------------------------------------------
#define ISC_IKH 0
#define ISC_IKL 16384
#define ISC_IQH 32768
#define ISC_IQL 49152
#define ISC_IW 65536

__global__ __launch_bounds__(256) void idx_score_mfma(const unsigned short* __restrict__ iqh,
                                                      const unsigned short* __restrict__ iql,
                                                      const unsigned short* __restrict__ ikh,
                                                      const unsigned short* __restrict__ ikl,
                                                      const float* __restrict__ iwbuf,
                                                      float* __restrict__ iscore) {
    const int kt = blockIdx.x, qt = blockIdx.y + 16;
    if (kt > qt) return;
    const int q0 = qt * 64, k0 = kt * 64;
    __shared__ __align__(16) unsigned char smem[69632];
    const int tid = threadIdx.x;
    const int w = tid >> 6, lane = tid & 63;
    const int g = lane >> 4, lr = lane & 15;

#pragma unroll
    for (int it = 0; it < 4; ++it) {
        const int j = tid + it * 256;
        const int row = j >> 4, slot = j & 15;
        const int dst = row * 256 + ((slot ^ (row & 7)) << 4);
        *(uint4*)(smem + ISC_IKH + dst) = *(const uint4*)(ikh + (size_t)(k0 + row) * 128 + slot * 8);
        *(uint4*)(smem + ISC_IKL + dst) = *(const uint4*)(ikl + (size_t)(k0 + row) * 128 + slot * 8);
    }
    {
        const int r = tid >> 2, c4 = (tid & 3) * 4;
        const float4 v = *(const float4*)(iwbuf + (size_t)(q0 + r) * 16 + c4);
        float4 sv = {v.x * 0.25f, v.y * 0.25f, v.z * 0.25f, v.w * 0.25f};
        *(float4*)(smem + ISC_IW + r * 64 + c4 * 4) = sv;
    }

    f32x4 tot[4];
#pragma unroll
    for (int j = 0; j < 4; ++j) tot[j] = (f32x4){0.f, 0.f, 0.f, 0.f};

    for (int n = 0; n < IDXH; ++n) {
        __syncthreads();
#pragma unroll
        for (int it = 0; it < 4; ++it) {
            const int j = tid + it * 256;
            const int row = j >> 4, slot = j & 15;
            const int dst = row * 256 + ((slot ^ (row & 7)) << 4);
            *(uint4*)(smem + ISC_IQH + dst) =
                *(const uint4*)(iqh + (size_t)(q0 + row) * 2048 + n * 128 + slot * 8);
            *(uint4*)(smem + ISC_IQL + dst) =
                *(const uint4*)(iql + (size_t)(q0 + row) * 2048 + n * 128 + slot * 8);
        }
        __syncthreads();

        bf16x8 aH[4], aL[4];
        const int ar = w * 16 + lr;
#pragma unroll
        for (int kk = 0; kk < 4; ++kk) {
            const int off = ar * 256 + (((kk * 4 + g) ^ (ar & 7)) << 4);
            aH[kk] = *(const bf16x8*)(smem + ISC_IQH + off);
            aL[kk] = *(const bf16x8*)(smem + ISC_IQL + off);
        }
        float wv[4];
#pragma unroll
        for (int r = 0; r < 4; ++r)
            wv[r] = *(const float*)(smem + ISC_IW + (w * 16 + g * 4 + r) * 64 + n * 4);

#pragma unroll
        for (int jj = 0; jj < 4; ++jj) {
            f32x4 s = (f32x4){0.f, 0.f, 0.f, 0.f};
#pragma unroll
            for (int kk = 0; kk < 4; ++kk) {
                const int br = jj * 16 + lr;
                const int off = br * 256 + (((kk * 4 + g) ^ (br & 7)) << 4);
                const bf16x8 bH = *(const bf16x8*)(smem + ISC_IKH + off);
                const bf16x8 bL = *(const bf16x8*)(smem + ISC_IKL + off);
                s = __builtin_amdgcn_mfma_f32_16x16x32_bf16(aH[kk], bH, s, 0, 0, 0);
                s = __builtin_amdgcn_mfma_f32_16x16x32_bf16(aH[kk], bL, s, 0, 0, 0);
                s = __builtin_amdgcn_mfma_f32_16x16x32_bf16(aL[kk], bH, s, 0, 0, 0);
            }
#pragma unroll
            for (int r = 0; r < 4; ++r) tot[jj][r] += wv[r] * fmaxf(s[r], 0.f);
        }
    }

    const float sc = 0.08838834764831845f;  // 1/sqrt(128)
#pragma unroll
    for (int jj = 0; jj < 4; ++jj)
#pragma unroll
        for (int r = 0; r < 4; ++r)
            iscore[(size_t)(q0 + w * 16 + g * 4 + r) * S_LEN + k0 + jj * 16 + lr] =
                tot[jj][r] * sc;
}

// ---------------------------------------------------------------------------
// Exact top-K per row -> BIT-PACKED mask (unchanged r9 radix select).
// ---------------------------------------------------------------------------
__global__ __launch_bounds__(256) void topk_kernel(const float* __restrict__ iscore,
                                                   unsigned char* __restrict__ maskb) {
    const int q = blockIdx.x;
    const int tid = threadIdx.x;
    const int nk = q + 1;
    unsigned char* mrow = maskb + (size_t)q * 256;
    if (nk <= KSEL) {
        unsigned char b = 0;
#pragma unroll
        for (int bi = 0; bi < 8; ++bi)
            if (tid * 8 + bi <= q) b |= (unsigned char)(1 << bi);
        mrow[tid] = b;
        return;
    }
    __shared__ unsigned int uv[S_LEN];
    __shared__ unsigned int hist[256];
    __shared__ unsigned int sh_pfx, sh_rem;
    const float* srow = iscore + (size_t)q * S_LEN;
    for (int k = tid; k < nk; k += 256) {
        unsigned int b = __float_as_uint(srow[k]);
        uv[k] = (b & 0x80000000u) ? ~b : (b | 0x80000000u);
    }
    if (tid == 0) { sh_pfx = 0u; sh_rem = KSEL; }
    __syncthreads();

    const int lane = tid & 63;
#pragma unroll
    for (int shift = 24; shift >= 0; shift -= 8) {
        const unsigned int pfx = sh_pfx;
        const unsigned int rem = sh_rem;
        const unsigned int pmask = (shift == 24) ? 0u : (0xFFFFFFFFu << (shift + 8));
        hist[tid] = 0u;
        __syncthreads();
        for (int k = tid; k < nk; k += 256) {
            const unsigned int u = uv[k];
            if ((u & pmask) == pfx)
                atomicAdd(&hist[(u >> shift) & 255u], 1u);
        }
        __syncthreads();
        const unsigned int h0 = hist[lane * 4], h1 = hist[lane * 4 + 1];
        const unsigned int h2 = hist[lane * 4 + 2], h3 = hist[lane * 4 + 3];
        unsigned int sufp = h0 + h1 + h2 + h3;
#pragma unroll
        for (int off = 1; off < 64; off <<= 1) {
            const unsigned int o = __shfl_down(sufp, off);
            if (lane + off < 64) sufp += o;
        }
        unsigned int run = __shfl_down(sufp, 1);
        if (lane == 63) run = 0u;
        const unsigned int s3 = run + h3;
        const unsigned int s2 = s3 + h2;
        const unsigned int s1 = s2 + h1;
        const unsigned int s0 = s1 + h0;
        int bsel = -1;
        unsigned int gt = 0u;
        if (s3 >= rem && run < rem)      { bsel = 3; gt = run; }
        else if (s2 >= rem && s3 < rem)  { bsel = 2; gt = s3; }
        else if (s1 >= rem && s2 < rem)  { bsel = 1; gt = s2; }
        else if (s0 >= rem && s1 < rem)  { bsel = 0; gt = s1; }
        if (bsel >= 0) {
            sh_pfx = pfx | ((unsigned int)(lane * 4 + bsel) << shift);
            sh_rem = rem - gt;
        }
        __syncthreads();
    }
    const unsigned int T = sh_pfx;
    const int r = (int)sh_rem;
    unsigned char b = 0;
#pragma unroll
    for (int bi = 0; bi < 8; ++bi) {
        const int k = tid * 8 + bi;
        if (k < nk) {
            const unsigned int u = uv[k];
            if (u > T) {
                b |= (unsigned char)(1 << bi);
            } else if (u == T) {
                int rank = 0;
                for (int j = 0; j < k; ++j) rank += (uv[j] == T) ? 1 : 0;
                if (rank < r) b |= (unsigned char)(1 << bi);
            }
        }
    }
    mrow[tid] = b;
}

// ---------------------------------------------------------------------------
// MFMA flash attention (r9/r12 structure, measured 113us) with LOAD-BALANCED
// qt pairing: first 256 blocks get qt=15..8, second 256 get qt=0..7 ASCENDING
// so each CU's two sequential blocks sum to exactly 34 tile-units.
// LDS: K0@0 K1@24576 (64x384 swz) | V0@49152 V1@65536 (128x128 swz) |
//      P@81920 (8x16x144) | M@100352 (128x256). Total 133120.
// ---------------------------------------------------------------------------
#define KVB 64
#define AQB 128
#define AT_K0 0
#define AT_V0 49152
#define AT_P 81920
#define AT_M 100352
#define AT_TOT 133120

__global__ __launch_bounds__(512) void attn_mfma_kernel(
    const unsigned short* __restrict__ qbuf16,
    const unsigned short* __restrict__ kb16,
    const unsigned short* __restrict__ vT,
    const unsigned char* __restrict__ maskb,
    unsigned short* __restrict__ ab16) {
    __shared__ __align__(16) unsigned char smem[AT_TOT];
    const int bid = blockIdx.x;
    const int xcd = bid & 7, jj = bid >> 3;
    const int h = (xcd << 2) | (jj & 3);   // 4 heads per XCD for L2 locality
    // balanced pairing: bid c and c+256 land on the same CU; their qt's are
    // (15-idx) and (idx) -> per-CU work = (2(15-idx)+2) + (2*idx+2) = 34 const.
    const int idx = (jj >> 2) & 7;
    const int qt = (jj & 32) ? idx : 15 - idx;
    const int q0 = qt * AQB;
    const int tid = threadIdx.x;
    const int w = tid >> 6, lane = tid & 63;
    const int g = lane >> 4, lr = lane & 15;
    const int wub = (tid & ~63) * 16;  // wave-uniform LDS dest component

    const unsigned char* kbase = (const unsigned char*)(kb16 + (size_t)h * S_LEN * D_QK);
    const unsigned char* vbase = (const unsigned char*)(vT + (size_t)h * 128 * S_LEN);
    const unsigned char* mbase = maskb + (size_t)q0 * 256;

    // Q fragments: wave w owns q rows q0 + w*16 .. +15
    bf16x8 qf[6];
    {
        const unsigned short* qrow =
            qbuf16 + (size_t)(q0 + w * 16 + lr) * (NHEAD * D_QK) + h * D_QK;
#pragma unroll
        for (int c = 0; c < 6; ++c) qf[c] = *(const bf16x8*)(qrow + c * 32 + g * 8);
    }

    // block mask (128 rows x 256B, contiguous) -> LDS once
#pragma unroll
    for (int it = 0; it < 4; ++it) {
        const int j = tid + it * 512;
        gload16(mbase + (size_t)j * 16, smem + AT_M + it * 8192 + wub);
    }

    // staging: linear LDS dest, inverse-swizzled global source (T21)
    auto stageK = [&](int k0, int kb) {
#pragma unroll
        for (int it = 0; it < 3; ++it) {
            const int j = tid + it * 512;
            const int row = j / 24, cs = j - row * 24;
            const int scs = (cs & ~7) | ((cs & 7) ^ (row & 7));
            gload16(kbase + (size_t)(k0 + row) * 384 + scs * 16, smem + kb + it * 8192 + wub);
        }
    };
    auto stageV = [&](int k0, int vb) {
#pragma unroll
        for (int it = 0; it < 2; ++it) {
            const int j = tid + it * 512;
            const int d = j >> 3, sl = j & 7;
            gload16(vbase + ((size_t)d * S_LEN + k0) * 2 + ((sl ^ (d & 7)) * 16),
                    smem + vb + it * 8192 + wub);
        }
    };

    f32x4 O[8];
#pragma unroll
    for (int db = 0; db < 8; ++db) O[db] = (f32x4){0.f, 0.f, 0.f, 0.f};
    float mS[4] = {-INFINITY, -INFINITY, -INFINITY, -INFINITY};
    float lS[4] = {0.f, 0.f, 0.f, 0.f};
    unsigned short* Pw = (unsigned short*)(smem + AT_P + w * 2304);

    const int nt = 2 * qt + 2;
    stageK(0, AT_K0);
    stageV(0, AT_V0);
    asm volatile("s_waitcnt vmcnt(0)" ::: "memory");
    __syncthreads();

    for (int t = 0; t < nt; ++t) {
        const int cK = AT_K0 + (t & 1) * 24576;
        const int cV = AT_V0 + (t & 1) * 16384;
        // issue next tile's DMA into the other buffer (hides under compute)
        if (t + 1 < nt) {
            stageK((t + 1) * KVB, AT_K0 + ((t + 1) & 1) * 24576);
            stageV((t + 1) * KVB, AT_V0 + ((t + 1) & 1) * 16384);
        }

        // ---- QK^T: S[16q][64k] per wave ----
        f32x4 a[4];
#pragma unroll
        for (int j = 0; j < 4; ++j) a[j] = (f32x4){0.f, 0.f, 0.f, 0.f};
        __builtin_amdgcn_s_setprio(1);
#pragma unroll
        for (int c = 0; c < 6; ++c) {
            const int s = c * 4 + g;  // 16B slot 0..23
#pragma unroll
            for (int j = 0; j < 4; ++j) {
                const int row = j * 16 + lr;
                const int scs = (s & ~7) | ((s & 7) ^ (lr & 7));
                const bf16x8 b = *(const bf16x8*)(smem + cK + row * 384 + scs * 16);
                a[j] = __builtin_amdgcn_mfma_f32_16x16x32_bf16(qf[c], b, a[j], 0, 0, 0);
            }
        }
        __builtin_amdgcn_s_setprio(0);

        // ---- online softmax over 64 keys (mask bits from LDS) ----
        const int moff = (t * KVB) >> 3;
        float corr[4];
#pragma unroll
        for (int r = 0; r < 4; ++r) {
            const int qrl = w * 16 + g * 4 + r;
            const unsigned int mlo = *(const unsigned int*)(smem + AT_M + qrl * 256 + moff);
            const unsigned int mhi = *(const unsigned int*)(smem + AT_M + qrl * 256 + moff + 4);
            float sv[4];
            sv[0] = ((mlo >> lr) & 1u) ? a[0][r] : -INFINITY;
            sv[1] = ((mlo >> (lr + 16)) & 1u) ? a[1][r] : -INFINITY;
            sv[2] = ((mhi >> lr) & 1u) ? a[2][r] : -INFINITY;
            sv[3] = ((mhi >> (lr + 16)) & 1u) ? a[3][r] : -INFINITY;
            float tm = fmaxf(fmaxf(sv[0], sv[1]), fmaxf(sv[2], sv[3]));
            tm = fmaxf(tm, __shfl_xor(tm, 1));
            tm = fmaxf(tm, __shfl_xor(tm, 2));
            tm = fmaxf(tm, __shfl_xor(tm, 4));
            tm = fmaxf(tm, __shfl_xor(tm, 8));
            const float mn = fmaxf(mS[r], tm);
            const float co = (mS[r] > -INFINITY) ? __expf(mS[r] - mn) : 0.f;
            float p[4];
#pragma unroll
            for (int j = 0; j < 4; ++j) p[j] = (sv[j] > -INFINITY) ? __expf(sv[j] - mn) : 0.f;
            float rs = (p[0] + p[1]) + (p[2] + p[3]);
            rs += __shfl_xor(rs, 1);
            rs += __shfl_xor(rs, 2);
            rs += __shfl_xor(rs, 4);
            rs += __shfl_xor(rs, 8);
            lS[r] = lS[r] * co + rs;
            mS[r] = mn;
            corr[r] = co;
#pragma unroll
            for (int j = 0; j < 4; ++j) Pw[(g * 4 + r) * 72 + j * 16 + lr] = f2b(p[j]);
        }
#pragma unroll
        for (int db = 0; db < 8; ++db) {
            O[db][0] *= corr[0];
            O[db][1] *= corr[1];
            O[db][2] *= corr[2];
            O[db][3] *= corr[3];
        }

        // own-wave P writes must land before re-read (rule 18)
        asm volatile("s_waitcnt lgkmcnt(0)" ::: "memory");
        __builtin_amdgcn_sched_barrier(0);

        // ---- PV: O[16q][128d] += P[16q][64k] * V[64k][128d] ----
        __builtin_amdgcn_s_setprio(1);
#pragma unroll
        for (int c2 = 0; c2 < 2; ++c2) {
            const bf16x8 pA = *(const bf16x8*)((const unsigned char*)Pw + lr * 144 + c2 * 64 + g * 16);
#pragma unroll
            for (int db = 0; db < 8; ++db) {
                const int d = db * 16 + lr;
                const int s2 = c2 * 4 + g;  // 16B slot 0..7
                const bf16x8 bV = *(const bf16x8*)(smem + cV + d * 128 + ((s2 ^ (d & 7)) << 4));
                O[db] = __builtin_amdgcn_mfma_f32_16x16x32_bf16(pA, bV, O[db], 0, 0, 0);
            }
        }
        __builtin_amdgcn_s_setprio(0);

        // staged next-tile DMA must complete before buffers swap
        asm volatile("s_waitcnt vmcnt(0)" ::: "memory");
        __syncthreads();
    }

    // ---- finalize ----
#pragma unroll
    for (int r = 0; r < 4; ++r) {
        const float inv = (lS[r] > 0.f) ? 1.f / lS[r] : 0.f;
        const int qg = q0 + w * 16 + g * 4 + r;
        unsigned short* orow = ab16 + (size_t)qg * (NHEAD * D_V) + h * D_V;
#pragma unroll
        for (int db = 0; db < 8; ++db) orow[db * 16 + lr] = f2b(O[db][r] * inv);
    }
}

// ---------------------------------------------------------------------------
extern "C" void kernel_launch(void* const* d_in, const int* in_sizes, int n_in,
                              void* d_out, int out_size, void* d_ws, size_t ws_size,
                              hipStream_t stream) {
    const float* hidden        = (const float*)d_in[0];
    const float* q_a_w         = (const float*)d_in[1];
    const float* q_a_norm_w    = (const float*)d_in[2];
    const float* q_b_w         = (const float*)d_in[3];
    const float* kv_a_w        = (const float*)d_in[4];
    const float* kv_a_norm_w   = (const float*)d_in[5];
    const float* kv_b_w        = (const float*)d_in[6];
    const float* o_w           = (const float*)d_in[7];
    const float* idx_wq_w      = (const float*)d_in[8];
    const float* idx_wk_w      = (const float*)d_in[9];
    const float* idx_weights_w = (const float*)d_in[10];
    float* out = (float*)d_out;

    char* ws = (char*)d_ws;
    // Z_A @0 (33.6M): BtAll -> owT
    unsigned short* BtAll = (unsigned short*)(ws + 0);
    unsigned short* owT   = (unsigned short*)(ws + 0);
    // Z_B @33.6M (33.6M): h16(hi)+h_lo -> qbuf16
    unsigned short* h16    = (unsigned short*)(ws + 33554432);
    unsigned short* h_lo   = (unsigned short*)(ws + 50331648);
    unsigned short* qbuf16 = (unsigned short*)(ws + 33554432);
    // Z_C @67108864 (17.8M): C1 -> vT
    float* C1          = (float*)(ws + 67108864);
    unsigned short* vT = (unsigned short*)(ws + 67108864);
    // Z_D @84934656 (37.7M): BtIdx hi/lo -> kb16
    unsigned short* BtIdxH = (unsigned short*)(ws + 84934656);
    unsigned short* BtIdxL = (unsigned short*)(ws + 103809024);
    unsigned short* kb16   = (unsigned short*)(ws + 84934656);
    // Z_E @122683392 (18.9M): Cidx -> qbT
    float* Cidx         = (float*)(ws + 122683392);
    unsigned short* qbT = (unsigned short*)(ws + 122683392);
    // Z_F @141557760 (17.8M): iqh/iql/ikh/ikl -> kvbT
    unsigned short* iqh  = (unsigned short*)(ws + 141557760);
    unsigned short* iql  = (unsigned short*)(ws + 149946368);
    unsigned short* ikh  = (unsigned short*)(ws + 158334976);
    unsigned short* ikl  = (unsigned short*)(ws + 158859264);
    unsigned short* kvbT = (unsigned short*)(ws + 141557760);
    // Z_G @159383552 (16.8M): iscr -> ab16
    float* iscr          = (float*)(ws + 159383552);
    unsigned short* ab16 = (unsigned short*)(ws + 159383552);
    // Z_H/Z_I
    unsigned char* maskb  = (unsigned char*)(ws + 176160768);  // [2048][256B] bit-packed
    unsigned short* qa16  = (unsigned short*)(ws + 180355072);
    unsigned short* kvn16 = (unsigned short*)(ws + 186646528);
    // Z_J: iwbuf fp32 [2048][16] + Cidx2 (split-K partial)
    float* iwbuf = (float*)(ws + 189005824);
    float* Cidx2 = (float*)(ws + 189136896);
    (void)ws_size; (void)in_sizes; (void)n_in; (void)out_size;

    const dim3 blk(256);
    const float QK_SCALE = 0.07216878364870323f;  // 1/sqrt(192)

    // hidden -> hi/lo bf16
    conv_split_h<<<8192, blk, 0, stream>>>(hidden, h16, h_lo);

    // stage-1 fused (q_a | kv_a | pad) and C1 = h @ W
    wtrans<<<dim3(24, 64), blk, 0, stream>>>(q_a_w, BtAll, HIDDEN, QRANK);
    wtrans<<<dim3(9, 64), blk, 0, stream>>>(kv_a_w, BtAll + (size_t)1536 * HIDDEN, HIDDEN, KVRANK + D_ROPE);
    wtrans<<<dim3(1, 64), blk, 0, stream>>>(q_a_w, BtAll + (size_t)2112 * HIDDEN, HIDDEN, 0);  // zeros
    gemm_bf16<0><<<dim3(17, 16), blk, 0, stream>>>(h16, BtAll, C1, HIDDEN, 2176, 1.f);

    rmsnormb<<<S_LEN, blk, 0, stream>>>(C1, q_a_norm_w, qa16, QRANK, 2176);
    rmsnormb<<<S_LEN, blk, 0, stream>>>(C1 + 1536, kv_a_norm_w, kvn16, KVRANK, 2176);

    // indexer: fused split-precision GEMM, compact XCD grid, split-K=2
    wtrans_split<<<dim3(32, 64), blk, 0, stream>>>(idx_wq_w, BtIdxH, BtIdxL, HIDDEN, IDXH * IDXD);
    wtrans_split<<<dim3(2, 64), blk, 0, stream>>>(idx_wk_w, BtIdxH + (size_t)2048 * HIDDEN,
                                                  BtIdxL + (size_t)2048 * HIDDEN, HIDDEN, IDXD);
    wtrans_split<<<dim3(2, 64), blk, 0, stream>>>(idx_weights_w, BtIdxH + (size_t)2176 * HIDDEN,
                                                  BtIdxL + (size_t)2176 * HIDDEN, HIDDEN, IDXH);
    gemm_split<<<dim3(304), blk, 0, stream>>>(h16, h_lo, BtIdxH, BtIdxL, Cidx, Cidx2);
    conv_split_iq<<<4384, blk, 0, stream>>>(Cidx, Cidx2, iqh, iql, ikh, ikl, iwbuf);
    idx_score_mfma<<<dim3(32, 16), blk, 0, stream>>>(iqh, iql, ikh, ikl, iwbuf, iscr);
    topk_kernel<<<S_LEN, blk, 0, stream>>>(iscr, maskb);

    // k_pe rope -> kb16 pe region (BtIdx dead after gemm_split; C1 still live)
    rope_k16b<<<(NHEAD * S_LEN * 32) / 256, blk, 0, stream>>>(C1, kb16);

    // stage-2 projections
    wtrans<<<dim3(96, 24), blk, 0, stream>>>(q_b_w, qbT, QRANK, NHEAD * D_QK);
    wtrans<<<dim3(128, 8), blk, 0, stream>>>(kv_b_w, kvbT, KVRANK, NHEAD * 256);
    gemm_bf16<1><<<dim3(48, 16), blk, 0, stream>>>(qa16, qbT, qbuf16, QRANK, NHEAD * D_QK, QK_SCALE);
    gemm_kvb<<<dim3(64, 16), blk, 0, stream>>>(kvn16, kvbT, kb16, vT);  // fused pack (C1 dead)
    rope_q16<<<(S_LEN * NHEAD * 32 + 255) / 256, blk, 0, stream>>>(qbuf16);

    // attention
    attn_mfma_kernel<<<dim3(512), dim3(512), 0, stream>>>(qbuf16, kb16, vT, maskb, ab16);

    // output projection
    wtrans<<<dim3(64, 64), blk, 0, stream>>>(o_w, owT, NHEAD * D_V, HIDDEN);
    gemm_bf16<0><<<dim3(32, 16), blk, 0, stream>>>(ab16, owT, out, NHEAD * D_V, HIDDEN, 1.f);
}

// Round 15
// 748.871 us; speedup vs baseline: 1.0307x; 1.0307x over previous
//
#include <hip/hip_runtime.h>
#include <math.h>

#define S_LEN 2048
#define HIDDEN 4096
#define NHEAD 32
#define D_NOPE 128
#define D_ROPE 64
#define D_V 128
#define D_QK 192
#define QRANK 1536
#define KVRANK 512
#define IDXH 16
#define IDXD 128
#define KSEL 1024
#define NIDX 2304  // 2048 (wq) + 128 (wk) + 16 (weights) + 112 pad

typedef __attribute__((ext_vector_type(8))) short bf16x8;
typedef __attribute__((ext_vector_type(4))) float f32x4;
typedef __attribute__((ext_vector_type(4))) unsigned short u16x4;

__device__ __forceinline__ unsigned short f2b(float f) {
    union { float f; unsigned int u; } x; x.f = f;
    unsigned int r = x.u + 0x7FFFu + ((x.u >> 16) & 1u);
    return (unsigned short)(r >> 16);
}
__device__ __forceinline__ float b2f(unsigned short u) {
    union { unsigned int u; float f; } x; x.u = ((unsigned int)u) << 16; return x.f;
}

// global -> LDS direct load, 16B per lane. LDS dest = wave-uniform base + lane*16.
__device__ __forceinline__ void gload16(const void* g, const void* l) {
    __builtin_amdgcn_global_load_lds(
        (const __attribute__((address_space(1))) unsigned int*)(unsigned long long)g,
        (__attribute__((address_space(3))) unsigned int*)(unsigned int)(unsigned long long)l,
        16, 0, 0);
}

// ---------------------------------------------------------------------------
// bf16 MFMA GEMM: C[M,N] = alpha * A[M,K] @ Bt[N,K]^T. 128x128 tile.
// Double-buffered counted-vmcnt pipeline + bijective XCD-chunk swizzle (T1).
// Requires grid size % 8 == 0.
// ---------------------------------------------------------------------------
template <int OUT_BF16>
__global__ __launch_bounds__(256) void gemm_bf16(const unsigned short* __restrict__ A,
                                                 const unsigned short* __restrict__ Bt,
                                                 void* __restrict__ Cv,
                                                 int K, int ldc, float alpha) {
    __shared__ __align__(16) unsigned char lds[32768];  // 2 x (As 8KB | Bs 8KB)
    const int tid = threadIdx.x;
    const int w = tid >> 6, lane = tid & 63;
    const int lr = lane & 15, g = lane >> 4;
    const int gx = gridDim.x;
    const int nwg = gx * gridDim.y;
    const int flat = blockIdx.y * gx + blockIdx.x;
    const int swz = (flat & 7) * (nwg >> 3) + (flat >> 3);
    const int bm = (swz / gx) * 128, bn = (swz % gx) * 128;
    const int wm = (w >> 1) * 64, wn = (w & 1) * 64;

    f32x4 acc[4][4];
#pragma unroll
    for (int i = 0; i < 4; ++i)
#pragma unroll
        for (int j = 0; j < 4; ++j) acc[i][j] = (f32x4){0.f, 0.f, 0.f, 0.f};

    int a_off[2], b_off[2];
#pragma unroll
    for (int issue = 0; issue < 2; ++issue) {
        const int off = issue * 4096 + w * 1024 + lane * 16;
        const int row = off >> 6, slot = (off >> 4) & 3;
        a_off[issue] = (bm + row) * K + ((slot ^ (row & 3)) << 3);
        b_off[issue] = (bn + row) * K + ((slot ^ (row & 3)) << 3);
    }

    const int KT = K >> 5;
    auto stage = [&](int t, int buf) {
        const int k0 = t << 5;
        unsigned char* l = lds + buf * 16384;
        gload16(A + a_off[0] + k0, l + w * 1024);
        gload16(A + a_off[1] + k0, l + 4096 + w * 1024);
        gload16(Bt + b_off[0] + k0, l + 8192 + w * 1024);
        gload16(Bt + b_off[1] + k0, l + 8192 + 4096 + w * 1024);
    };

    stage(0, 0);
    for (int t = 0; t < KT; ++t) {
        if (t + 1 < KT) {
            stage(t + 1, (t + 1) & 1);
            asm volatile("s_waitcnt vmcnt(4)" ::: "memory");  // tile t landed
        } else {
            asm volatile("s_waitcnt vmcnt(0)" ::: "memory");
        }
        __syncthreads();
        const unsigned char* l = lds + (t & 1) * 16384;

        bf16x8 af[4], bfr[4];
#pragma unroll
        for (int i = 0; i < 4; ++i) {
            const int rowA = wm + i * 16 + lr;
            af[i] = *(const bf16x8*)(l + rowA * 64 + ((g ^ (rowA & 3)) << 4));
            const int rowB = wn + i * 16 + lr;
            bfr[i] = *(const bf16x8*)(l + 8192 + rowB * 64 + ((g ^ (rowB & 3)) << 4));
        }
#pragma unroll
        for (int i = 0; i < 4; ++i)
#pragma unroll
            for (int j = 0; j < 4; ++j)
                acc[i][j] = __builtin_amdgcn_mfma_f32_16x16x32_bf16(af[i], bfr[j], acc[i][j], 0, 0, 0);
        __syncthreads();
    }

#pragma unroll
    for (int i = 0; i < 4; ++i) {
        const int m = bm + wm + i * 16 + g * 4;
#pragma unroll
        for (int j = 0; j < 4; ++j) {
            const int n = bn + wn + j * 16 + lr;
            if (OUT_BF16) {
                unsigned short* Cb = (unsigned short*)Cv;
#pragma unroll
                for (int r = 0; r < 4; ++r)
                    Cb[(size_t)(m + r) * ldc + n] = f2b(acc[i][j][r] * alpha);
            } else {
                float* Cf = (float*)Cv;
#pragma unroll
                for (int r = 0; r < 4; ++r)
                    Cf[(size_t)(m + r) * ldc + n] = acc[i][j][r] * alpha;
            }
        }
    }
}

// ---------------------------------------------------------------------------
// kv_b GEMM with fused pack epilogue. A = kvn16 [2048][512], Bt = kvbT
// [8192][512]. Even 128-col blocks (d<128 of a head) -> kb16[h][s][192] nope;
// odd blocks (v) -> LDS-transpose -> vT[h*128+d][s]. Grid (64,16).
// ---------------------------------------------------------------------------
__global__ __launch_bounds__(256) void gemm_kvb(const unsigned short* __restrict__ A,
                                                const unsigned short* __restrict__ Bt,
                                                unsigned short* __restrict__ kb16,
                                                unsigned short* __restrict__ vT) {
    __shared__ __align__(16) unsigned char lds[34816];  // loop: 32KB dbuf; epi: 128x136 u16
    const int tid = threadIdx.x;
    const int w = tid >> 6, lane = tid & 63;
    const int lr = lane & 15, g = lane >> 4;
    const int gx = gridDim.x;
    const int nwg = gx * gridDim.y;
    const int flat = blockIdx.y * gx + blockIdx.x;
    const int swz = (flat & 7) * (nwg >> 3) + (flat >> 3);
    const int bm = (swz / gx) * 128, bn = (swz % gx) * 128;
    const int wm = (w >> 1) * 64, wn = (w & 1) * 64;
    const int K = KVRANK;

    f32x4 acc[4][4];
#pragma unroll
    for (int i = 0; i < 4; ++i)
#pragma unroll
        for (int j = 0; j < 4; ++j) acc[i][j] = (f32x4){0.f, 0.f, 0.f, 0.f};

    int a_off[2], b_off[2];
#pragma unroll
    for (int issue = 0; issue < 2; ++issue) {
        const int off = issue * 4096 + w * 1024 + lane * 16;
        const int row = off >> 6, slot = (off >> 4) & 3;
        a_off[issue] = (bm + row) * K + ((slot ^ (row & 3)) << 3);
        b_off[issue] = (bn + row) * K + ((slot ^ (row & 3)) << 3);
    }

    const int KT = K >> 5;
    auto stage = [&](int t, int buf) {
        const int k0 = t << 5;
        unsigned char* l = lds + buf * 16384;
        gload16(A + a_off[0] + k0, l + w * 1024);
        gload16(A + a_off[1] + k0, l + 4096 + w * 1024);
        gload16(Bt + b_off[0] + k0, l + 8192 + w * 1024);
        gload16(Bt + b_off[1] + k0, l + 8192 + 4096 + w * 1024);
    };

    stage(0, 0);
    for (int t = 0; t < KT; ++t) {
        if (t + 1 < KT) {
            stage(t + 1, (t + 1) & 1);
            asm volatile("s_waitcnt vmcnt(4)" ::: "memory");
        } else {
            asm volatile("s_waitcnt vmcnt(0)" ::: "memory");
        }
        __syncthreads();
        const unsigned char* l = lds + (t & 1) * 16384;

        bf16x8 af[4], bfr[4];
#pragma unroll
        for (int i = 0; i < 4; ++i) {
            const int rowA = wm + i * 16 + lr;
            af[i] = *(const bf16x8*)(l + rowA * 64 + ((g ^ (rowA & 3)) << 4));
            const int rowB = wn + i * 16 + lr;
            bfr[i] = *(const bf16x8*)(l + 8192 + rowB * 64 + ((g ^ (rowB & 3)) << 4));
        }
#pragma unroll
        for (int i = 0; i < 4; ++i)
#pragma unroll
            for (int j = 0; j < 4; ++j)
                acc[i][j] = __builtin_amdgcn_mfma_f32_16x16x32_bf16(af[i], bfr[j], acc[i][j], 0, 0, 0);
        __syncthreads();
    }

    const int h = bn >> 8;
    if ((bn & 128) == 0) {
        // k_nope columns -> kb16[h][s][192], d = wn + j*16 + lr (0..127)
#pragma unroll
        for (int i = 0; i < 4; ++i) {
            const int m = bm + wm + i * 16 + g * 4;
#pragma unroll
            for (int j = 0; j < 4; ++j) {
                const int dl = wn + j * 16 + lr;
#pragma unroll
                for (int r = 0; r < 4; ++r)
                    kb16[((size_t)h * S_LEN + m + r) * D_QK + dl] = f2b(acc[i][j][r]);
            }
        }
    } else {
        // V columns -> transpose via LDS -> vT[h*128+d][s]
        unsigned short(*T)[136] = (unsigned short(*)[136])lds;
#pragma unroll
        for (int i = 0; i < 4; ++i) {
            const int ml = wm + i * 16 + g * 4;
#pragma unroll
            for (int j = 0; j < 4; ++j) {
                const int dl = wn + j * 16 + lr;
#pragma unroll
                for (int r = 0; r < 4; ++r) T[dl][ml + r] = f2b(acc[i][j][r]);
            }
        }
        __syncthreads();
        const int row = tid >> 1, half = tid & 1;
        unsigned short* dst = vT + (size_t)(h * 128 + row) * S_LEN + bm + half * 64;
        const unsigned short* src = &T[row][half * 64];
#pragma unroll
        for (int u = 0; u < 8; ++u)  // full 64 u16 per half-row
            *(uint4*)(dst + u * 8) = *(const uint4*)(src + u * 8);
    }
}

// ---------------------------------------------------------------------------
// Split-precision (hi/lo bf16) MFMA GEMM for the indexer (unchanged r9).
// ---------------------------------------------------------------------------
__global__ __launch_bounds__(256) void gemm_split(const unsigned short* __restrict__ Ah,
                                                  const unsigned short* __restrict__ Al,
                                                  const unsigned short* __restrict__ Bh,
                                                  const unsigned short* __restrict__ Bl,
                                                  float* __restrict__ C0,
                                                  float* __restrict__ C1) {
    const int K = HIDDEN, ldc = NIDX;
    const int bid = blockIdx.x;              // 304 = 8 * 38
    const int wf = (bid & 7) * 38 + (bid >> 3);
    const int kz = (wf >= 152) ? 1 : 0;
    const int wgid = wf - kz * 152;
    int x, y;
    if (wgid < 144) { y = 8 + wgid / 18; x = wgid % 18; }
    else            { x = 16; y = wgid - 144; }
    const int bm = y * 128, bn = x * 128;
    float* __restrict__ C = kz ? C1 : C0;

    __shared__ __align__(16) unsigned char lds[65536];
    const int tid = threadIdx.x;
    const int w = tid >> 6, lane = tid & 63;
    const int lr = lane & 15, g = lane >> 4;
    const int wm = (w >> 1) * 64, wn = (w & 1) * 64;

    f32x4 acc[4][4];
#pragma unroll
    for (int i = 0; i < 4; ++i)
#pragma unroll
        for (int j = 0; j < 4; ++j) acc[i][j] = (f32x4){0.f, 0.f, 0.f, 0.f};

    int a_off[2], b_off[2];
#pragma unroll
    for (int issue = 0; issue < 2; ++issue) {
        const int off = issue * 4096 + w * 1024 + lane * 16;
        const int row = off >> 6, slot = (off >> 4) & 3;
        a_off[issue] = (bm + row) * K + ((slot ^ (row & 3)) << 3) + kz * 2048;
        b_off[issue] = (bn + row) * K + ((slot ^ (row & 3)) << 3) + kz * 2048;
    }

    const int KT = 2048 >> 5;
    auto stage = [&](int t, int buf) {
        const int k0 = t << 5;
        unsigned char* l = lds + buf * 32768;
        gload16(Ah + a_off[0] + k0, l + w * 1024);
        gload16(Ah + a_off[1] + k0, l + 4096 + w * 1024);
        gload16(Al + a_off[0] + k0, l + 8192 + w * 1024);
        gload16(Al + a_off[1] + k0, l + 8192 + 4096 + w * 1024);
        gload16(Bh + b_off[0] + k0, l + 16384 + w * 1024);
        gload16(Bh + b_off[1] + k0, l + 16384 + 4096 + w * 1024);
        gload16(Bl + b_off[0] + k0, l + 24576 + w * 1024);
        gload16(Bl + b_off[1] + k0, l + 24576 + 4096 + w * 1024);
    };

    stage(0, 0);
    for (int t = 0; t < KT; ++t) {
        if (t + 1 < KT) {
            stage(t + 1, (t + 1) & 1);
            asm volatile("s_waitcnt vmcnt(8)" ::: "memory");
        } else {
            asm volatile("s_waitcnt vmcnt(0)" ::: "memory");
        }
        __syncthreads();
        const unsigned char* l = lds + (t & 1) * 32768;

        bf16x8 afh[4], afl[4], bfh[4], bfl[4];
#pragma unroll
        for (int i = 0; i < 4; ++i) {
            const int rowA = wm + i * 16 + lr;
            const int offA = rowA * 64 + ((g ^ (rowA & 3)) << 4);
            afh[i] = *(const bf16x8*)(l + offA);
            afl[i] = *(const bf16x8*)(l + 8192 + offA);
            const int rowB = wn + i * 16 + lr;
            const int offB = rowB * 64 + ((g ^ (rowB & 3)) << 4);
            bfh[i] = *(const bf16x8*)(l + 16384 + offB);
            bfl[i] = *(const bf16x8*)(l + 24576 + offB);
        }
#pragma unroll
        for (int i = 0; i < 4; ++i)
#pragma unroll
            for (int j = 0; j < 4; ++j) {
                acc[i][j] = __builtin_amdgcn_mfma_f32_16x16x32_bf16(afh[i], bfh[j], acc[i][j], 0, 0, 0);
                acc[i][j] = __builtin_amdgcn_mfma_f32_16x16x32_bf16(afh[i], bfl[j], acc[i][j], 0, 0, 0);
                acc[i][j] = __builtin_amdgcn_mfma_f32_16x16x32_bf16(afl[i], bfh[j], acc[i][j], 0, 0, 0);
            }
        __syncthreads();
    }

#pragma unroll
    for (int i = 0; i < 4; ++i) {
        const int m = bm + wm + i * 16 + g * 4;
#pragma unroll
        for (int j = 0; j < 4; ++j) {
            const int n = bn + wn + j * 16 + lr;
#pragma unroll
            for (int r = 0; r < 4; ++r)
                C[(size_t)(m + r) * ldc + n] = acc[i][j][r];
        }
    }
}

// ---------------------------------------------------------------------------
// fp32 -> (hi, lo) bf16 pair, 4 elems/thread
// ---------------------------------------------------------------------------
__global__ __launch_bounds__(256) void conv_split_h(const float* __restrict__ src,
                                                    unsigned short* __restrict__ dhi,
                                                    unsigned short* __restrict__ dlo) {
    const int i = blockIdx.x * 256 + threadIdx.x;
    const float4 v = ((const float4*)src)[i];
    u16x4 hi, lo;
    const float xs[4] = {v.x, v.y, v.z, v.w};
#pragma unroll
    for (int j = 0; j < 4; ++j) {
        const unsigned short h = f2b(xs[j]);
        hi[j] = h;
        lo[j] = f2b(xs[j] - b2f(h));
    }
    *(u16x4*)(dhi + (size_t)i * 4) = hi;
    *(u16x4*)(dlo + (size_t)i * 4) = lo;
}

// Sum split-K partials, then split (unchanged r9).
__global__ __launch_bounds__(256) void conv_split_iq(const float* __restrict__ C0,
                                                     const float* __restrict__ C1,
                                                     unsigned short* __restrict__ iqh,
                                                     unsigned short* __restrict__ iql,
                                                     unsigned short* __restrict__ ikh,
                                                     unsigned short* __restrict__ ikl,
                                                     float* __restrict__ iwbuf) {
    const int i = blockIdx.x * 256 + threadIdx.x;  // over 2048*548
    const int row = i / 548, c4 = (i - row * 548) * 4;
    const float4 v0 = *(const float4*)(C0 + (size_t)row * NIDX + c4);
    const float4 v1 = *(const float4*)(C1 + (size_t)row * NIDX + c4);
    const float xs[4] = {v0.x + v1.x, v0.y + v1.y, v0.z + v1.z, v0.w + v1.w};
    if (c4 >= 2176) {
        *(float4*)(iwbuf + (size_t)row * 16 + (c4 - 2176)) =
            (float4){xs[0], xs[1], xs[2], xs[3]};
        return;
    }
    u16x4 hi, lo;
#pragma unroll
    for (int j = 0; j < 4; ++j) {
        const unsigned short h = f2b(xs[j]);
        hi[j] = h;
        lo[j] = f2b(xs[j] - b2f(h));
    }
    if (c4 < 2048) {
        *(u16x4*)(iqh + (size_t)row * 2048 + c4) = hi;
        *(u16x4*)(iql + (size_t)row * 2048 + c4) = lo;
    } else {
        *(u16x4*)(ikh + (size_t)row * 128 + c4 - 2048) = hi;
        *(u16x4*)(ikl + (size_t)row * 128 + c4 - 2048) = lo;
    }
}

// ---------------------------------------------------------------------------
// Weight transpose-convert kernels (unchanged)
// ---------------------------------------------------------------------------
__global__ __launch_bounds__(256) void wtrans(const float* __restrict__ W,
                                              unsigned short* __restrict__ Bt,
                                              int K, int Nsrc) {
    const int n0 = blockIdx.x * 64, k0 = blockIdx.y * 64;
    __shared__ unsigned short lv[64][72];
    const int tid = threadIdx.x;
#pragma unroll
    for (int it = 0; it < 16; ++it) {
        const int idx = tid + it * 256;
        const int kr = idx >> 6, n = idx & 63;
        const float v = (n0 + n < Nsrc) ? W[(size_t)(k0 + kr) * Nsrc + n0 + n] : 0.f;
        lv[n][kr] = f2b(v);
    }
    __syncthreads();
#pragma unroll
    for (int it = 0; it < 16; ++it) {
        const int idx = tid + it * 256;
        const int n = idx >> 6, kk = idx & 63;
        Bt[(size_t)(n0 + n) * K + k0 + kk] = lv[n][kk];
    }
}

__global__ __launch_bounds__(256) void wtrans_split(const float* __restrict__ W,
                                                    unsigned short* __restrict__ Bth,
                                                    unsigned short* __restrict__ Btl,
                                                    int K, int Nsrc) {
    const int n0 = blockIdx.x * 64, k0 = blockIdx.y * 64;
    __shared__ float lv[64][65];
    const int tid = threadIdx.x;
#pragma unroll
    for (int it = 0; it < 16; ++it) {
        const int idx = tid + it * 256;
        const int kr = idx >> 6, n = idx & 63;
        lv[n][kr] = (n0 + n < Nsrc) ? W[(size_t)(k0 + kr) * Nsrc + n0 + n] : 0.f;
    }
    __syncthreads();
#pragma unroll
    for (int it = 0; it < 16; ++it) {
        const int idx = tid + it * 256;
        const int n = idx >> 6, kk = idx & 63;
        const float x = lv[n][kk];
        const unsigned short h = f2b(x);
        Bth[(size_t)(n0 + n) * K + k0 + kk] = h;
        Btl[(size_t)(n0 + n) * K + k0 + kk] = f2b(x - b2f(h));
    }
}

// ---------------------------------------------------------------------------
// RMSNorm fp32 in (strided) -> bf16 out
// ---------------------------------------------------------------------------
__global__ __launch_bounds__(256) void rmsnormb(const float* __restrict__ in,
                                                const float* __restrict__ w,
                                                unsigned short* __restrict__ out,
                                                int W, int in_stride) {
    const int row = blockIdx.x;
    const int tid = threadIdx.x;
    const float* x = in + (size_t)row * in_stride;
    float ss = 0.f;
    for (int i = tid; i < W; i += 256) {
        float v = x[i];
        ss += v * v;
    }
    __shared__ float red[256];
    red[tid] = ss;
    __syncthreads();
    for (int s = 128; s > 0; s >>= 1) {
        if (tid < s) red[tid] += red[tid + s];
        __syncthreads();
    }
    const float scale = rsqrtf(red[0] / (float)W + 1e-5f);
    for (int i = tid; i < W; i += 256) out[(size_t)row * W + i] = f2b(x[i] * scale * w[i]);
}

// ---------------------------------------------------------------------------
// RoPE kernels
// ---------------------------------------------------------------------------
__global__ __launch_bounds__(256) void rope_q16(unsigned short* __restrict__ q) {
    const int idx = blockIdx.x * 256 + threadIdx.x;
    if (idx >= S_LEN * NHEAD * (D_ROPE / 2)) return;
    const int i = idx & 31;
    const int h = (idx >> 5) & 31;
    const int s = idx >> 10;
    const float inv = __expf(-(float)i * (logf(10000.f) / 32.f));
    const float ang = (float)s * inv;
    const float cs = cosf(ang), sn = sinf(ang);
    unsigned short* p = q + (size_t)s * (NHEAD * D_QK) + h * D_QK + D_NOPE + 2 * i;
    const float x0 = b2f(p[0]), x1 = b2f(p[1]);
    p[0] = f2b(x0 * cs - x1 * sn);
    p[1] = f2b(x1 * cs + x0 * sn);
}

// RoPE k_pe from C1 (stride 2176, cols 2048..2111) broadcast into all heads of
// kb16[h][s][128+2i..].
__global__ __launch_bounds__(256) void rope_k16b(const float* __restrict__ C1,
                                                 unsigned short* __restrict__ kb16) {
    const int idx = blockIdx.x * 256 + threadIdx.x;
    const int i = idx & 31;
    const int s = (idx >> 5) & 2047;
    const int h = idx >> 16;
    const float inv = __expf(-(float)i * (logf(10000.f) / 32.f));
    const float ang = (float)s * inv;
    const float cs = cosf(ang), sn = sinf(ang);
    const float* p = C1 + (size_t)s * 2176 + 2048 + 2 * i;
    const float x0 = p[0], x1 = p[1];
    unsigned short* o = kb16 + ((size_t)h * S_LEN + s) * D_QK + D_NOPE + 2 * i;
    o[0] = f2b(x0 * cs - x1 * sn);
    o[1] = f2b(x1 * cs + x0 * sn);
}

// ---------------------------------------------------------------------------
// Indexer scores via split-bf16 MFMA (unchanged r9).
// ---------------------------------------------------------------------------
#define ISC_IKH 0
#define ISC_IKL 16384
#define ISC_IQH 32768
#define ISC_IQL 49152
#define ISC_IW 65536

__global__ __launch_bounds__(256) void idx_score_mfma(const unsigned short* __restrict__ iqh,
                                                      const unsigned short* __restrict__ iql,
                                                      const unsigned short* __restrict__ ikh,
                                                      const unsigned short* __restrict__ ikl,
                                                      const float* __restrict__ iwbuf,
                                                      float* __restrict__ iscore) {
    const int kt = blockIdx.x, qt = blockIdx.y + 16;
    if (kt > qt) return;
    const int q0 = qt * 64, k0 = kt * 64;
    __shared__ __align__(16) unsigned char smem[69632];
    const int tid = threadIdx.x;
    const int w = tid >> 6, lane = tid & 63;
    const int g = lane >> 4, lr = lane & 15;

#pragma unroll
    for (int it = 0; it < 4; ++it) {
        const int j = tid + it * 256;
        const int row = j >> 4, slot = j & 15;
        const int dst = row * 256 + ((slot ^ (row & 7)) << 4);
        *(uint4*)(smem + ISC_IKH + dst) = *(const uint4*)(ikh + (size_t)(k0 + row) * 128 + slot * 8);
        *(uint4*)(smem + ISC_IKL + dst) = *(const uint4*)(ikl + (size_t)(k0 + row) * 128 + slot * 8);
    }
    {
        const int r = tid >> 2, c4 = (tid & 3) * 4;
        const float4 v = *(const float4*)(iwbuf + (size_t)(q0 + r) * 16 + c4);
        float4 sv = {v.x * 0.25f, v.y * 0.25f, v.z * 0.25f, v.w * 0.25f};
        *(float4*)(smem + ISC_IW + r * 64 + c4 * 4) = sv;
    }

    f32x4 tot[4];
#pragma unroll
    for (int j = 0; j < 4; ++j) tot[j] = (f32x4){0.f, 0.f, 0.f, 0.f};

    for (int n = 0; n < IDXH; ++n) {
        __syncthreads();
#pragma unroll
        for (int it = 0; it < 4; ++it) {
            const int j = tid + it * 256;
            const int row = j >> 4, slot = j & 15;
            const int dst = row * 256 + ((slot ^ (row & 7)) << 4);
            *(uint4*)(smem + ISC_IQH + dst) =
                *(const uint4*)(iqh + (size_t)(q0 + row) * 2048 + n * 128 + slot * 8);
            *(uint4*)(smem + ISC_IQL + dst) =
                *(const uint4*)(iql + (size_t)(q0 + row) * 2048 + n * 128 + slot * 8);
        }
        __syncthreads();

        bf16x8 aH[4], aL[4];
        const int ar = w * 16 + lr;
#pragma unroll
        for (int kk = 0; kk < 4; ++kk) {
            const int off = ar * 256 + (((kk * 4 + g) ^ (ar & 7)) << 4);
            aH[kk] = *(const bf16x8*)(smem + ISC_IQH + off);
            aL[kk] = *(const bf16x8*)(smem + ISC_IQL + off);
        }
        float wv[4];
#pragma unroll
        for (int r = 0; r < 4; ++r)
            wv[r] = *(const float*)(smem + ISC_IW + (w * 16 + g * 4 + r) * 64 + n * 4);

#pragma unroll
        for (int jj = 0; jj < 4; ++jj) {
            f32x4 s = (f32x4){0.f, 0.f, 0.f, 0.f};
#pragma unroll
            for (int kk = 0; kk < 4; ++kk) {
                const int br = jj * 16 + lr;
                const int off = br * 256 + (((kk * 4 + g) ^ (br & 7)) << 4);
                const bf16x8 bH = *(const bf16x8*)(smem + ISC_IKH + off);
                const bf16x8 bL = *(const bf16x8*)(smem + ISC_IKL + off);
                s = __builtin_amdgcn_mfma_f32_16x16x32_bf16(aH[kk], bH, s, 0, 0, 0);
                s = __builtin_amdgcn_mfma_f32_16x16x32_bf16(aH[kk], bL, s, 0, 0, 0);
                s = __builtin_amdgcn_mfma_f32_16x16x32_bf16(aL[kk], bH, s, 0, 0, 0);
            }
#pragma unroll
            for (int r = 0; r < 4; ++r) tot[jj][r] += wv[r] * fmaxf(s[r], 0.f);
        }
    }

    const float sc = 0.08838834764831845f;  // 1/sqrt(128)
#pragma unroll
    for (int jj = 0; jj < 4; ++jj)
#pragma unroll
        for (int r = 0; r < 4; ++r)
            iscore[(size_t)(q0 + w * 16 + g * 4 + r) * S_LEN + k0 + jj * 16 + lr] =
                tot[jj][r] * sc;
}

// ---------------------------------------------------------------------------
// Exact top-K per row -> BIT-PACKED mask (unchanged r9 radix select).
// ---------------------------------------------------------------------------
__global__ __launch_bounds__(256) void topk_kernel(const float* __restrict__ iscore,
                                                   unsigned char* __restrict__ maskb) {
    const int q = blockIdx.x;
    const int tid = threadIdx.x;
    const int nk = q + 1;
    unsigned char* mrow = maskb + (size_t)q * 256;
    if (nk <= KSEL) {
        unsigned char b = 0;
#pragma unroll
        for (int bi = 0; bi < 8; ++bi)
            if (tid * 8 + bi <= q) b |= (unsigned char)(1 << bi);
        mrow[tid] = b;
        return;
    }
    __shared__ unsigned int uv[S_LEN];
    __shared__ unsigned int hist[256];
    __shared__ unsigned int sh_pfx, sh_rem;
    const float* srow = iscore + (size_t)q * S_LEN;
    for (int k = tid; k < nk; k += 256) {
        unsigned int b = __float_as_uint(srow[k]);
        uv[k] = (b & 0x80000000u) ? ~b : (b | 0x80000000u);
    }
    if (tid == 0) { sh_pfx = 0u; sh_rem = KSEL; }
    __syncthreads();

    const int lane = tid & 63;
#pragma unroll
    for (int shift = 24; shift >= 0; shift -= 8) {
        const unsigned int pfx = sh_pfx;
        const unsigned int rem = sh_rem;
        const unsigned int pmask = (shift == 24) ? 0u : (0xFFFFFFFFu << (shift + 8));
        hist[tid] = 0u;
        __syncthreads();
        for (int k = tid; k < nk; k += 256) {
            const unsigned int u = uv[k];
            if ((u & pmask) == pfx)
                atomicAdd(&hist[(u >> shift) & 255u], 1u);
        }
        __syncthreads();
        const unsigned int h0 = hist[lane * 4], h1 = hist[lane * 4 + 1];
        const unsigned int h2 = hist[lane * 4 + 2], h3 = hist[lane * 4 + 3];
        unsigned int sufp = h0 + h1 + h2 + h3;
#pragma unroll
        for (int off = 1; off < 64; off <<= 1) {
            const unsigned int o = __shfl_down(sufp, off);
            if (lane + off < 64) sufp += o;
        }
        unsigned int run = __shfl_down(sufp, 1);
        if (lane == 63) run = 0u;
        const unsigned int s3 = run + h3;
        const unsigned int s2 = s3 + h2;
        const unsigned int s1 = s2 + h1;
        const unsigned int s0 = s1 + h0;
        int bsel = -1;
        unsigned int gt = 0u;
        if (s3 >= rem && run < rem)      { bsel = 3; gt = run; }
        else if (s2 >= rem && s3 < rem)  { bsel = 2; gt = s3; }
        else if (s1 >= rem && s2 < rem)  { bsel = 1; gt = s2; }
        else if (s0 >= rem && s1 < rem)  { bsel = 0; gt = s1; }
        if (bsel >= 0) {
            sh_pfx = pfx | ((unsigned int)(lane * 4 + bsel) << shift);
            sh_rem = rem - gt;
        }
        __syncthreads();
    }
    const unsigned int T = sh_pfx;
    const int r = (int)sh_rem;
    unsigned char b = 0;
#pragma unroll
    for (int bi = 0; bi < 8; ++bi) {
        const int k = tid * 8 + bi;
        if (k < nk) {
            const unsigned int u = uv[k];
            if (u > T) {
                b |= (unsigned char)(1 << bi);
            } else if (u == T) {
                int rank = 0;
                for (int j = 0; j < k; ++j) rank += (uv[j] == T) ? 1 : 0;
                if (rank < r) b |= (unsigned char)(1 << bi);
            }
        }
    }
    mrow[tid] = b;
}

// ---------------------------------------------------------------------------
// MFMA flash attention (round-9 structure, measured 113us): QBLK=128, 8 waves,
// KVB=64, double-buffered global_load_lds staging with pre-swizzled sources
// (T21), block mask resident in LDS, XCD-grouped 1D grid (4 heads per XCD).
// LDS: K0@0 K1@24576 (64x384 swz) | V0@49152 V1@65536 (128x128 swz) |
//      P@81920 (8x16x144) | M@100352 (128x256). Total 133120.
// ---------------------------------------------------------------------------
#define KVB 64
#define AQB 128
#define AT_K0 0
#define AT_V0 49152
#define AT_P 81920
#define AT_M 100352
#define AT_TOT 133120

__global__ __launch_bounds__(512) void attn_mfma_kernel(
    const unsigned short* __restrict__ qbuf16,
    const unsigned short* __restrict__ kb16,
    const unsigned short* __restrict__ vT,
    const unsigned char* __restrict__ maskb,
    unsigned short* __restrict__ ab16) {
    __shared__ __align__(16) unsigned char smem[AT_TOT];
    const int bid = blockIdx.x;
    const int xcd = bid & 7, jj = bid >> 3;
    const int h = (xcd << 2) | (jj & 3);   // 4 heads per XCD for L2 locality
    const int qt = 15 - (jj >> 2);         // heavy q-tiles dispatched first (LPT)
    const int q0 = qt * AQB;
    const int tid = threadIdx.x;
    const int w = tid >> 6, lane = tid & 63;
    const int g = lane >> 4, lr = lane & 15;
    const int wub = (tid & ~63) * 16;  // wave-uniform LDS dest component

    const unsigned char* kbase = (const unsigned char*)(kb16 + (size_t)h * S_LEN * D_QK);
    const unsigned char* vbase = (const unsigned char*)(vT + (size_t)h * 128 * S_LEN);
    const unsigned char* mbase = maskb + (size_t)q0 * 256;

    // Q fragments: wave w owns q rows q0 + w*16 .. +15
    bf16x8 qf[6];
    {
        const unsigned short* qrow =
            qbuf16 + (size_t)(q0 + w * 16 + lr) * (NHEAD * D_QK) + h * D_QK;
#pragma unroll
        for (int c = 0; c < 6; ++c) qf[c] = *(const bf16x8*)(qrow + c * 32 + g * 8);
    }

    // block mask (128 rows x 256B, contiguous) -> LDS once
#pragma unroll
    for (int it = 0; it < 4; ++it) {
        const int j = tid + it * 512;
        gload16(mbase + (size_t)j * 16, smem + AT_M + it * 8192 + wub);
    }

    // staging: linear LDS dest, inverse-swizzled global source (T21)
    auto stageK = [&](int k0, int kb) {
#pragma unroll
        for (int it = 0; it < 3; ++it) {
            const int j = tid + it * 512;
            const int row = j / 24, cs = j - row * 24;
            const int scs = (cs & ~7) | ((cs & 7) ^ (row & 7));
            gload16(kbase + (size_t)(k0 + row) * 384 + scs * 16, smem + kb + it * 8192 + wub);
        }
    };
    auto stageV = [&](int k0, int vb) {
#pragma unroll
        for (int it = 0; it < 2; ++it) {
            const int j = tid + it * 512;
            const int d = j >> 3, sl = j & 7;
            gload16(vbase + ((size_t)d * S_LEN + k0) * 2 + ((sl ^ (d & 7)) * 16),
                    smem + vb + it * 8192 + wub);
        }
    };

    f32x4 O[8];
#pragma unroll
    for (int db = 0; db < 8; ++db) O[db] = (f32x4){0.f, 0.f, 0.f, 0.f};
    float mS[4] = {-INFINITY, -INFINITY, -INFINITY, -INFINITY};
    float lS[4] = {0.f, 0.f, 0.f, 0.f};
    unsigned short* Pw = (unsigned short*)(smem + AT_P + w * 2304);

    const int nt = 2 * qt + 2;
    stageK(0, AT_K0);
    stageV(0, AT_V0);
    asm volatile("s_waitcnt vmcnt(0)" ::: "memory");
    __syncthreads();

    for (int t = 0; t < nt; ++t) {
        const int cK = AT_K0 + (t & 1) * 24576;
        const int cV = AT_V0 + (t & 1) * 16384;
        // issue next tile's DMA into the other buffer (hides under compute)
        if (t + 1 < nt) {
            stageK((t + 1) * KVB, AT_K0 + ((t + 1) & 1) * 24576);
            stageV((t + 1) * KVB, AT_V0 + ((t + 1) & 1) * 16384);
        }

        // ---- QK^T: S[16q][64k] per wave ----
        f32x4 a[4];
#pragma unroll
        for (int j = 0; j < 4; ++j) a[j] = (f32x4){0.f, 0.f, 0.f, 0.f};
        __builtin_amdgcn_s_setprio(1);
#pragma unroll
        for (int c = 0; c < 6; ++c) {
            const int s = c * 4 + g;  // 16B slot 0..23
#pragma unroll
            for (int j = 0; j < 4; ++j) {
                const int row = j * 16 + lr;
                const int scs = (s & ~7) | ((s & 7) ^ (lr & 7));
                const bf16x8 b = *(const bf16x8*)(smem + cK + row * 384 + scs * 16);
                a[j] = __builtin_amdgcn_mfma_f32_16x16x32_bf16(qf[c], b, a[j], 0, 0, 0);
            }
        }
        __builtin_amdgcn_s_setprio(0);

        // ---- online softmax over 64 keys (mask bits from LDS) ----
        const int moff = (t * KVB) >> 3;
        float corr[4];
#pragma unroll
        for (int r = 0; r < 4; ++r) {
            const int qrl = w * 16 + g * 4 + r;
            const unsigned int mlo = *(const unsigned int*)(smem + AT_M + qrl * 256 + moff);
            const unsigned int mhi = *(const unsigned int*)(smem + AT_M + qrl * 256 + moff + 4);
            float sv[4];
            sv[0] = ((mlo >> lr) & 1u) ? a[0][r] : -INFINITY;
            sv[1] = ((mlo >> (lr + 16)) & 1u) ? a[1][r] : -INFINITY;
            sv[2] = ((mhi >> lr) & 1u) ? a[2][r] : -INFINITY;
            sv[3] = ((mhi >> (lr + 16)) & 1u) ? a[3][r] : -INFINITY;
            float tm = fmaxf(fmaxf(sv[0], sv[1]), fmaxf(sv[2], sv[3]));
            tm = fmaxf(tm, __shfl_xor(tm, 1));
            tm = fmaxf(tm, __shfl_xor(tm, 2));
            tm = fmaxf(tm, __shfl_xor(tm, 4));
            tm = fmaxf(tm, __shfl_xor(tm, 8));
            const float mn = fmaxf(mS[r], tm);
            const float co = (mS[r] > -INFINITY) ? __expf(mS[r] - mn) : 0.f;
            float p[4];
#pragma unroll
            for (int j = 0; j < 4; ++j) p[j] = (sv[j] > -INFINITY) ? __expf(sv[j] - mn) : 0.f;
            float rs = (p[0] + p[1]) + (p[2] + p[3]);
            rs += __shfl_xor(rs, 1);
            rs += __shfl_xor(rs, 2);
            rs += __shfl_xor(rs, 4);
            rs += __shfl_xor(rs, 8);
            lS[r] = lS[r] * co + rs;
            mS[r] = mn;
            corr[r] = co;
#pragma unroll
            for (int j = 0; j < 4; ++j) Pw[(g * 4 + r) * 72 + j * 16 + lr] = f2b(p[j]);
        }
#pragma unroll
        for (int db = 0; db < 8; ++db) {
            O[db][0] *= corr[0];
            O[db][1] *= corr[1];
            O[db][2] *= corr[2];
            O[db][3] *= corr[3];
        }

        // own-wave P writes must land before re-read (rule 18)
        asm volatile("s_waitcnt lgkmcnt(0)" ::: "memory");
        __builtin_amdgcn_sched_barrier(0);

        // ---- PV: O[16q][128d] += P[16q][64k] * V[64k][128d] ----
        __builtin_amdgcn_s_setprio(1);
#pragma unroll
        for (int c2 = 0; c2 < 2; ++c2) {
            const bf16x8 pA = *(const bf16x8*)((const unsigned char*)Pw + lr * 144 + c2 * 64 + g * 16);
#pragma unroll
            for (int db = 0; db < 8; ++db) {
                const int d = db * 16 + lr;
                const int s2 = c2 * 4 + g;  // 16B slot 0..7
                const bf16x8 bV = *(const bf16x8*)(smem + cV + d * 128 + ((s2 ^ (d & 7)) << 4));
                O[db] = __builtin_amdgcn_mfma_f32_16x16x32_bf16(pA, bV, O[db], 0, 0, 0);
            }
        }
        __builtin_amdgcn_s_setprio(0);

        // staged next-tile DMA must complete before buffers swap
        asm volatile("s_waitcnt vmcnt(0)" ::: "memory");
        __syncthreads();
    }

    // ---- finalize ----
#pragma unroll
    for (int r = 0; r < 4; ++r) {
        const float inv = (lS[r] > 0.f) ? 1.f / lS[r] : 0.f;
        const int qg = q0 + w * 16 + g * 4 + r;
        unsigned short* orow = ab16 + (size_t)qg * (NHEAD * D_V) + h * D_V;
#pragma unroll
        for (int db = 0; db < 8; ++db) orow[db * 16 + lr] = f2b(O[db][r] * inv);
    }
}

// ---------------------------------------------------------------------------
extern "C" void kernel_launch(void* const* d_in, const int* in_sizes, int n_in,
                              void* d_out, int out_size, void* d_ws, size_t ws_size,
                              hipStream_t stream) {
    const float* hidden        = (const float*)d_in[0];
    const float* q_a_w         = (const float*)d_in[1];
    const float* q_a_norm_w    = (const float*)d_in[2];
    const float* q_b_w         = (const float*)d_in[3];
    const float* kv_a_w        = (const float*)d_in[4];
    const float* kv_a_norm_w   = (const float*)d_in[5];
    const float* kv_b_w        = (const float*)d_in[6];
    const float* o_w           = (const float*)d_in[7];
    const float* idx_wq_w      = (const float*)d_in[8];
    const float* idx_wk_w      = (const float*)d_in[9];
    const float* idx_weights_w = (const float*)d_in[10];
    float* out = (float*)d_out;

    char* ws = (char*)d_ws;
    // Z_A @0 (33.6M): BtAll -> owT
    unsigned short* BtAll = (unsigned short*)(ws + 0);
    unsigned short* owT   = (unsigned short*)(ws + 0);
    // Z_B @33.6M (33.6M): h16(hi)+h_lo -> qbuf16
    unsigned short* h16    = (unsigned short*)(ws + 33554432);
    unsigned short* h_lo   = (unsigned short*)(ws + 50331648);
    unsigned short* qbuf16 = (unsigned short*)(ws + 33554432);
    // Z_C @67108864 (17.8M): C1 -> vT
    float* C1          = (float*)(ws + 67108864);
    unsigned short* vT = (unsigned short*)(ws + 67108864);
    // Z_D @84934656 (37.7M): BtIdx hi/lo -> kb16
    unsigned short* BtIdxH = (unsigned short*)(ws + 84934656);
    unsigned short* BtIdxL = (unsigned short*)(ws + 103809024);
    unsigned short* kb16   = (unsigned short*)(ws + 84934656);
    // Z_E @122683392 (18.9M): Cidx -> qbT
    float* Cidx         = (float*)(ws + 122683392);
    unsigned short* qbT = (unsigned short*)(ws + 122683392);
    // Z_F @141557760 (17.8M): iqh/iql/ikh/ikl -> kvbT
    unsigned short* iqh  = (unsigned short*)(ws + 141557760);
    unsigned short* iql  = (unsigned short*)(ws + 149946368);
    unsigned short* ikh  = (unsigned short*)(ws + 158334976);
    unsigned short* ikl  = (unsigned short*)(ws + 158859264);
    unsigned short* kvbT = (unsigned short*)(ws + 141557760);
    // Z_G @159383552 (16.8M): iscr -> ab16
    float* iscr          = (float*)(ws + 159383552);
    unsigned short* ab16 = (unsigned short*)(ws + 159383552);
    // Z_H/Z_I
    unsigned char* maskb  = (unsigned char*)(ws + 176160768);  // [2048][256B] bit-packed
    unsigned short* qa16  = (unsigned short*)(ws + 180355072);
    unsigned short* kvn16 = (unsigned short*)(ws + 186646528);
    // Z_J: iwbuf fp32 [2048][16] + Cidx2 (split-K partial)
    float* iwbuf = (float*)(ws + 189005824);
    float* Cidx2 = (float*)(ws + 189136896);
    (void)ws_size; (void)in_sizes; (void)n_in; (void)out_size;

    const dim3 blk(256);
    const float QK_SCALE = 0.07216878364870323f;  // 1/sqrt(192)

    // hidden -> hi/lo bf16
    conv_split_h<<<8192, blk, 0, stream>>>(hidden, h16, h_lo);

    // stage-1 fused (q_a | kv_a | pad) and C1 = h @ W
    wtrans<<<dim3(24, 64), blk, 0, stream>>>(q_a_w, BtAll, HIDDEN, QRANK);
    wtrans<<<dim3(9, 64), blk, 0, stream>>>(kv_a_w, BtAll + (size_t)1536 * HIDDEN, HIDDEN, KVRANK + D_ROPE);
    wtrans<<<dim3(1, 64), blk, 0, stream>>>(q_a_w, BtAll + (size_t)2112 * HIDDEN, HIDDEN, 0);  // zeros
    gemm_bf16<0><<<dim3(17, 16), blk, 0, stream>>>(h16, BtAll, C1, HIDDEN, 2176, 1.f);

    rmsnormb<<<S_LEN, blk, 0, stream>>>(C1, q_a_norm_w, qa16, QRANK, 2176);
    rmsnormb<<<S_LEN, blk, 0, stream>>>(C1 + 1536, kv_a_norm_w, kvn16, KVRANK, 2176);

    // indexer: fused split-precision GEMM, compact XCD grid, split-K=2
    wtrans_split<<<dim3(32, 64), blk, 0, stream>>>(idx_wq_w, BtIdxH, BtIdxL, HIDDEN, IDXH * IDXD);
    wtrans_split<<<dim3(2, 64), blk, 0, stream>>>(idx_wk_w, BtIdxH + (size_t)2048 * HIDDEN,
                                                  BtIdxL + (size_t)2048 * HIDDEN, HIDDEN, IDXD);
    wtrans_split<<<dim3(2, 64), blk, 0, stream>>>(idx_weights_w, BtIdxH + (size_t)2176 * HIDDEN,
                                                  BtIdxL + (size_t)2176 * HIDDEN, HIDDEN, IDXH);
    gemm_split<<<dim3(304), blk, 0, stream>>>(h16, h_lo, BtIdxH, BtIdxL, Cidx, Cidx2);
    conv_split_iq<<<4384, blk, 0, stream>>>(Cidx, Cidx2, iqh, iql, ikh, ikl, iwbuf);
    idx_score_mfma<<<dim3(32, 16), blk, 0, stream>>>(iqh, iql, ikh, ikl, iwbuf, iscr);
    topk_kernel<<<S_LEN, blk, 0, stream>>>(iscr, maskb);

    // k_pe rope -> kb16 pe region (BtIdx dead after gemm_split; C1 still live)
    rope_k16b<<<(NHEAD * S_LEN * 32) / 256, blk, 0, stream>>>(C1, kb16);

    // stage-2 projections
    wtrans<<<dim3(96, 24), blk, 0, stream>>>(q_b_w, qbT, QRANK, NHEAD * D_QK);
    wtrans<<<dim3(128, 8), blk, 0, stream>>>(kv_b_w, kvbT, KVRANK, NHEAD * 256);
    gemm_bf16<1><<<dim3(48, 16), blk, 0, stream>>>(qa16, qbT, qbuf16, QRANK, NHEAD * D_QK, QK_SCALE);
    gemm_kvb<<<dim3(64, 16), blk, 0, stream>>>(kvn16, kvbT, kb16, vT);  // fused pack (C1 dead)
    rope_q16<<<(S_LEN * NHEAD * 32 + 255) / 256, blk, 0, stream>>>(qbuf16);

    // attention
    attn_mfma_kernel<<<dim3(512), dim3(512), 0, stream>>>(qbuf16, kb16, vT, maskb, ab16);

    // output projection
    wtrans<<<dim3(64, 64), blk, 0, stream>>>(o_w, owT, NHEAD * D_V, HIDDEN);
    gemm_bf16<0><<<dim3(32, 16), blk, 0, stream>>>(ab16, owT, out, NHEAD * D_V, HIDDEN, 1.f);
}